// Round 1
// baseline (830.037 us; speedup 1.0000x reference)
//
#include <hip/hip_runtime.h>

// DeepReservoir: out = concat(h0, h1, h2), B=65536, IN=256, U=512
// h0 = sine(x@(W0*M0)+b0); h1 = sine(h0@(W1*M1)+b1) + x@(S1*SM1); h2 likewise.
// Strategy: prep kernel packs masked bf16 weights in MFMA B-fragment layout into ws;
// main kernel fuses all 3 layers per 64-row tile using 16x16x32 bf16 MFMA.

#define IN_DIM 256
#define UNITS  512
#define OUTC   1536

typedef __bf16 bf16x8 __attribute__((ext_vector_type(8)));
typedef unsigned short us8 __attribute__((ext_vector_type(8)));
typedef unsigned short us4 __attribute__((ext_vector_type(4)));
typedef float f32x4 __attribute__((ext_vector_type(4)));

// element offsets (bf16) of each packed matrix inside ws
#define W0OFF 0
#define W1OFF 131072
#define W2OFF 393216
#define S1OFF 655360
#define S2OFF 786432

__device__ __forceinline__ unsigned short f2bf(float f) {
    unsigned u = __float_as_uint(f);
    u += 0x7FFFu + ((u >> 16) & 1u);   // round-to-nearest-even
    return (unsigned short)(u >> 16);
}

// ---------------- prep: masked weights -> bf16, packed B-fragment layout ----------------
// Fragment (kf, nb): k in [kf*32, kf*32+32), n in [nb*16, nb*16+16).
// Lane l holds B[k = kf*32 + (l>>4)*8 + i][n = nb*16 + (l&15)], i=0..7 -> 16B per lane.
__global__ __launch_bounds__(256) void prep_weights(
    const float* __restrict__ W0, const float* __restrict__ M0,
    const float* __restrict__ W1, const float* __restrict__ M1,
    const float* __restrict__ W2, const float* __restrict__ M2,
    const float* __restrict__ S1, const float* __restrict__ SM1,
    const float* __restrict__ S2, const float* __restrict__ SM2,
    unsigned short* __restrict__ ws)
{
    int g = blockIdx.x * 256 + threadIdx.x;  // fragment-lane id, 0..114687
    const float* W; const float* M; int obase; int q;
    if (g < 16384)      { W = W0; M = M0;  obase = W0OFF; q = g; }
    else if (g < 49152) { W = W1; M = M1;  obase = W1OFF; q = g - 16384; }
    else if (g < 81920) { W = W2; M = M2;  obase = W2OFF; q = g - 49152; }
    else if (g < 98304) { W = S1; M = SM1; obase = S1OFF; q = g - 81920; }
    else                { W = S2; M = SM2; obase = S2OFF; q = g - 98304; }
    int frag = q >> 6, lane = q & 63;
    int kf = frag >> 5, nb = frag & 31;
    int k0 = kf * 32 + (lane >> 4) * 8;
    int n  = nb * 16 + (lane & 15);
    us8 o;
#pragma unroll
    for (int i = 0; i < 8; ++i) {
        size_t idx = (size_t)(k0 + i) * UNITS + n;
        o[i] = f2bf(W[idx] * M[idx]);
    }
    *(us8*)(ws + obase + (size_t)q * 8) = o;
}

// ---------------- main fused kernel ----------------
// 512 threads = 8 waves; block handles 64 batch rows; wave w -> cols [w*64, w*64+64).
// LDS: xs = 64 rows x 256 bf16 (pitch 512B, XOR-swizzled), hs = 64 x 512 bf16 (pitch 1024B).
template<int KF, int PITCH>
__device__ __forceinline__ void mm_acc(f32x4 (&acc)[4][4],
    const unsigned char* __restrict__ lsrc,
    const unsigned short* __restrict__ wfrag,   // matrix base + nb0*512 elements
    int lane)
{
    const int lcol = lane & 15, lhi = lane >> 4;
#pragma unroll
    for (int kf = 0; kf < KF; ++kf) {
        bf16x8 a[4];
#pragma unroll
        for (int r = 0; r < 4; ++r) {
            int row = r * 16 + lcol;
            unsigned off = (unsigned)(row * PITCH + (kf * 32 + lhi * 8) * 2);
            off ^= (unsigned)((row & 7) << 4);
            a[r] = __builtin_bit_cast(bf16x8, *(const us8*)(lsrc + off));
        }
#pragma unroll
        for (int c = 0; c < 4; ++c) {
            us8 bw = *(const us8*)(wfrag + (size_t)((kf * 32 + c) * 64 + lane) * 8);
            bf16x8 b = __builtin_bit_cast(bf16x8, bw);
#pragma unroll
            for (int r = 0; r < 4; ++r)
                acc[r][c] = __builtin_amdgcn_mfma_f32_16x16x32_bf16(a[r], b, acc[r][c], 0, 0, 0);
        }
    }
}

__global__ __launch_bounds__(512, 2) void reservoir_main(
    const float* __restrict__ x,
    const unsigned short* __restrict__ wb,
    const float* __restrict__ b0, const float* __restrict__ b1, const float* __restrict__ b2,
    const float* __restrict__ pf0, const float* __restrict__ pa0, const float* __restrict__ pd0,
    const float* __restrict__ pf1, const float* __restrict__ pa1, const float* __restrict__ pd1,
    const float* __restrict__ pf2, const float* __restrict__ pa2, const float* __restrict__ pd2,
    float* __restrict__ out)
{
    __shared__ __align__(16) unsigned char lds[98304];
    unsigned char* xs = lds;            // 32 KB
    unsigned char* hs = lds + 32768;    // 64 KB

    const int t = threadIdx.x;
    const int wave = t >> 6, lane = t & 63;
    const int lcol = lane & 15, lhi = lane >> 4;
    const long rb = (long)blockIdx.x * 64;
    const int cb = wave * 64;
    const unsigned nb0e = (unsigned)(wave * 4) * 512;  // element offset of wave's first fragment column

    const float f0v = pf0[0], a0v = pa0[0], d0v = pd0[0];
    const float f1v = pf1[0], a1v = pa1[0], d1v = pd1[0];
    const float f2v = pf2[0], a2v = pa2[0], d2v = pd2[0];

    // ---- stage x tile -> bf16 LDS (swizzled) ----
    {
        int r  = t >> 3;
        int c0 = (t & 7) * 32;
        const float* xp = x + (rb + r) * IN_DIM + c0;
        unsigned base = (unsigned)(r * 512 + c0 * 2);
        unsigned swz  = (unsigned)((r & 7) << 4);
#pragma unroll
        for (int j = 0; j < 8; ++j) {
            f32x4 v = *(const f32x4*)(xp + j * 4);
            us4 h;
            h[0] = f2bf(v[0]); h[1] = f2bf(v[1]); h[2] = f2bf(v[2]); h[3] = f2bf(v[3]);
            *(us4*)(xs + ((base + (unsigned)j * 8) ^ swz)) = h;
        }
    }
    __syncthreads();

    f32x4 acc[4][4];

    // =================== layer 0: h0 = sine(x@W0m + b0) ===================
#pragma unroll
    for (int r = 0; r < 4; ++r)
#pragma unroll
        for (int c = 0; c < 4; ++c) acc[r][c] = (f32x4){0.f, 0.f, 0.f, 0.f};

    mm_acc<8, 512>(acc, xs, wb + W0OFF + nb0e, lane);

#pragma unroll
    for (int c = 0; c < 4; ++c) {
        int col = cb + c * 16 + lcol;
        float bias = b0[col];
#pragma unroll
        for (int r = 0; r < 4; ++r) {
#pragma unroll
            for (int j = 0; j < 4; ++j) {
                int row = r * 16 + lhi * 4 + j;
                float z = acc[r][c][j] + bias;
                float h = a0v * __sinf(f0v * z) * __expf(-d0v * fabsf(z));
                out[(rb + row) * OUTC + col] = h;
                unsigned off = ((unsigned)(row * 1024 + col * 2)) ^ ((unsigned)((row & 7) << 4));
                *(unsigned short*)(hs + off) = f2bf(h);
            }
        }
    }
    __syncthreads();

    // =================== layer 1: h1 = sine(h0@W1m + b1) + x@S1m ===================
#pragma unroll
    for (int r = 0; r < 4; ++r)
#pragma unroll
        for (int c = 0; c < 4; ++c) acc[r][c] = (f32x4){0.f, 0.f, 0.f, 0.f};

    mm_acc<16, 1024>(acc, hs, wb + W1OFF + nb0e, lane);

#pragma unroll
    for (int c = 0; c < 4; ++c) {
        int col = cb + c * 16 + lcol;
        float bias = b1[col];
#pragma unroll
        for (int r = 0; r < 4; ++r) {
#pragma unroll
            for (int j = 0; j < 4; ++j) {
                float z = acc[r][c][j] + bias;
                acc[r][c][j] = a1v * __sinf(f1v * z) * __expf(-d1v * fabsf(z));
            }
        }
    }
    mm_acc<8, 512>(acc, xs, wb + S1OFF + nb0e, lane);   // accumulate skip on top
    __syncthreads();   // all waves done reading h0 before overwriting hs

#pragma unroll
    for (int c = 0; c < 4; ++c) {
        int col = cb + c * 16 + lcol;
#pragma unroll
        for (int r = 0; r < 4; ++r) {
#pragma unroll
            for (int j = 0; j < 4; ++j) {
                int row = r * 16 + lhi * 4 + j;
                float h = acc[r][c][j];
                out[(rb + row) * OUTC + UNITS + col] = h;
                unsigned off = ((unsigned)(row * 1024 + col * 2)) ^ ((unsigned)((row & 7) << 4));
                *(unsigned short*)(hs + off) = f2bf(h);
            }
        }
    }
    __syncthreads();

    // =================== layer 2: h2 = sine(h1@W2m + b2) + x@S2m ===================
#pragma unroll
    for (int r = 0; r < 4; ++r)
#pragma unroll
        for (int c = 0; c < 4; ++c) acc[r][c] = (f32x4){0.f, 0.f, 0.f, 0.f};

    mm_acc<16, 1024>(acc, hs, wb + W2OFF + nb0e, lane);

#pragma unroll
    for (int c = 0; c < 4; ++c) {
        int col = cb + c * 16 + lcol;
        float bias = b2[col];
#pragma unroll
        for (int r = 0; r < 4; ++r) {
#pragma unroll
            for (int j = 0; j < 4; ++j) {
                float z = acc[r][c][j] + bias;
                acc[r][c][j] = a2v * __sinf(f2v * z) * __expf(-d2v * fabsf(z));
            }
        }
    }
    mm_acc<8, 512>(acc, xs, wb + S2OFF + nb0e, lane);

#pragma unroll
    for (int c = 0; c < 4; ++c) {
        int col = cb + c * 16 + lcol;
#pragma unroll
        for (int r = 0; r < 4; ++r) {
#pragma unroll
            for (int j = 0; j < 4; ++j) {
                int row = r * 16 + lhi * 4 + j;
                out[(rb + row) * OUTC + 2 * UNITS + col] = acc[r][c][j];
            }
        }
    }
}

extern "C" void kernel_launch(void* const* d_in, const int* in_sizes, int n_in,
                              void* d_out, int out_size, void* d_ws, size_t ws_size,
                              hipStream_t stream)
{
    (void)in_sizes; (void)n_in; (void)out_size; (void)ws_size;
    const float* x   = (const float*)d_in[0];
    const float* W0  = (const float*)d_in[1];
    const float* b0  = (const float*)d_in[2];
    const float* M0  = (const float*)d_in[3];
    const float* f0  = (const float*)d_in[4];
    const float* a0  = (const float*)d_in[5];
    const float* d0  = (const float*)d_in[6];
    const float* W1  = (const float*)d_in[7];
    const float* b1  = (const float*)d_in[8];
    const float* M1  = (const float*)d_in[9];
    const float* f1  = (const float*)d_in[10];
    const float* a1  = (const float*)d_in[11];
    const float* d1  = (const float*)d_in[12];
    const float* S1  = (const float*)d_in[13];
    const float* SM1 = (const float*)d_in[14];
    const float* W2  = (const float*)d_in[15];
    const float* b2  = (const float*)d_in[16];
    const float* M2  = (const float*)d_in[17];
    const float* f2  = (const float*)d_in[18];
    const float* a2  = (const float*)d_in[19];
    const float* d2  = (const float*)d_in[20];
    const float* S2  = (const float*)d_in[21];
    const float* SM2 = (const float*)d_in[22];

    unsigned short* wb = (unsigned short*)d_ws;
    float* out = (float*)d_out;

    prep_weights<<<448, 256, 0, stream>>>(W0, M0, W1, M1, W2, M2, S1, SM1, S2, SM2, wb);
    reservoir_main<<<65536 / 64, 512, 0, stream>>>(x, wb, b0, b1, b2,
                                                   f0, a0, d0, f1, a1, d1, f2, a2, d2, out);
}

// Round 3
// 827.985 us; speedup vs baseline: 1.0025x; 1.0025x over previous
//
#include <hip/hip_runtime.h>

// DeepReservoir: out = concat(h0, h1, h2), B=65536, IN=256, U=512
// h0 = sine(x@(W0*M0)+b0); h1 = sine(h0@(W1*M1)+b1) + x@(S1*SM1); h2 likewise.
// Strategy: prep kernel packs masked bf16 weights in MFMA B-fragment layout into ws;
// main kernel fuses all 3 layers per 32-row tile using 16x16x32 bf16 MFMA.
// R1: 32-row blocks (48KB LDS) -> 2 blocks/CU co-resident (occupancy 23%->~46%).
// R2: resubmit unchanged (R1 bench lost to GPUAcquisitionTimeout).

#define IN_DIM 256
#define UNITS  512
#define OUTC   1536

typedef __bf16 bf16x8 __attribute__((ext_vector_type(8)));
typedef unsigned short us8 __attribute__((ext_vector_type(8)));
typedef unsigned short us4 __attribute__((ext_vector_type(4)));
typedef float f32x4 __attribute__((ext_vector_type(4)));

// element offsets (bf16) of each packed matrix inside ws
#define W0OFF 0
#define W1OFF 131072
#define W2OFF 393216
#define S1OFF 655360
#define S2OFF 786432

__device__ __forceinline__ unsigned short f2bf(float f) {
    unsigned u = __float_as_uint(f);
    u += 0x7FFFu + ((u >> 16) & 1u);   // round-to-nearest-even
    return (unsigned short)(u >> 16);
}

// ---------------- prep: masked weights -> bf16, packed B-fragment layout ----------------
// Fragment (kf, nb): k in [kf*32, kf*32+32), n in [nb*16, nb*16+16).
// Lane l holds B[k = kf*32 + (l>>4)*8 + i][n = nb*16 + (l&15)], i=0..7 -> 16B per lane.
__global__ __launch_bounds__(256) void prep_weights(
    const float* __restrict__ W0, const float* __restrict__ M0,
    const float* __restrict__ W1, const float* __restrict__ M1,
    const float* __restrict__ W2, const float* __restrict__ M2,
    const float* __restrict__ S1, const float* __restrict__ SM1,
    const float* __restrict__ S2, const float* __restrict__ SM2,
    unsigned short* __restrict__ ws)
{
    int g = blockIdx.x * 256 + threadIdx.x;  // fragment-lane id, 0..114687
    const float* W; const float* M; int obase; int q;
    if (g < 16384)      { W = W0; M = M0;  obase = W0OFF; q = g; }
    else if (g < 49152) { W = W1; M = M1;  obase = W1OFF; q = g - 16384; }
    else if (g < 81920) { W = W2; M = M2;  obase = W2OFF; q = g - 49152; }
    else if (g < 98304) { W = S1; M = SM1; obase = S1OFF; q = g - 81920; }
    else                { W = S2; M = SM2; obase = S2OFF; q = g - 98304; }
    int frag = q >> 6, lane = q & 63;
    int kf = frag >> 5, nb = frag & 31;
    int k0 = kf * 32 + (lane >> 4) * 8;
    int n  = nb * 16 + (lane & 15);
    us8 o;
#pragma unroll
    for (int i = 0; i < 8; ++i) {
        size_t idx = (size_t)(k0 + i) * UNITS + n;
        o[i] = f2bf(W[idx] * M[idx]);
    }
    *(us8*)(ws + obase + (size_t)q * 8) = o;
}

// ---------------- main fused kernel ----------------
// 512 threads = 8 waves; block handles 32 batch rows; wave w -> cols [w*64, w*64+64).
// LDS: xs = 32 x 256 bf16 (pitch 512B, XOR-swizzled), hs = 32 x 512 bf16 (pitch 1024B).
template<int KF, int PITCH>
__device__ __forceinline__ void mm_acc(f32x4 (&acc)[2][4],
    const unsigned char* __restrict__ lsrc,
    const unsigned short* __restrict__ wfrag,   // matrix base + nb0*512 elements
    int lane)
{
    const int lcol = lane & 15, lhi = lane >> 4;
#pragma unroll
    for (int kf = 0; kf < KF; ++kf) {
        bf16x8 a[2];
#pragma unroll
        for (int r = 0; r < 2; ++r) {
            int row = r * 16 + lcol;
            unsigned off = (unsigned)(row * PITCH + (kf * 32 + lhi * 8) * 2);
            off ^= (unsigned)((row & 7) << 4);
            a[r] = __builtin_bit_cast(bf16x8, *(const us8*)(lsrc + off));
        }
#pragma unroll
        for (int c = 0; c < 4; ++c) {
            us8 bw = *(const us8*)(wfrag + (size_t)((kf * 32 + c) * 64 + lane) * 8);
            bf16x8 b = __builtin_bit_cast(bf16x8, bw);
#pragma unroll
            for (int r = 0; r < 2; ++r)
                acc[r][c] = __builtin_amdgcn_mfma_f32_16x16x32_bf16(a[r], b, acc[r][c], 0, 0, 0);
        }
    }
}

__global__ __launch_bounds__(512, 4) void reservoir_main(
    const float* __restrict__ x,
    const unsigned short* __restrict__ wb,
    const float* __restrict__ b0, const float* __restrict__ b1, const float* __restrict__ b2,
    const float* __restrict__ pf0, const float* __restrict__ pa0, const float* __restrict__ pd0,
    const float* __restrict__ pf1, const float* __restrict__ pa1, const float* __restrict__ pd1,
    const float* __restrict__ pf2, const float* __restrict__ pa2, const float* __restrict__ pd2,
    float* __restrict__ out)
{
    __shared__ __align__(16) unsigned char lds[49152];
    unsigned char* xs = lds;            // 16 KB
    unsigned char* hs = lds + 16384;    // 32 KB

    const int t = threadIdx.x;
    const int wave = t >> 6, lane = t & 63;
    const int lcol = lane & 15, lhi = lane >> 4;
    const long rb = (long)blockIdx.x * 32;
    const int cb = wave * 64;
    const unsigned nb0e = (unsigned)(wave * 4) * 512;  // element offset of wave's first fragment column

    const float f0v = pf0[0], a0v = pa0[0], d0v = pd0[0];
    const float f1v = pf1[0], a1v = pa1[0], d1v = pd1[0];
    const float f2v = pf2[0], a2v = pa2[0], d2v = pd2[0];

    // ---- stage x tile -> bf16 LDS (swizzled); lane-contiguous 256B per load instr ----
    {
        int r  = t >> 4;            // 0..31
        int cq = (t & 15) * 4;      // float col within 64-float group
        const float* xp = x + (rb + r) * IN_DIM + cq;
        unsigned base = (unsigned)(r * 512 + cq * 2);
        unsigned swz  = (unsigned)((r & 7) << 4);
#pragma unroll
        for (int j = 0; j < 4; ++j) {
            f32x4 v = *(const f32x4*)(xp + j * 64);
            us4 h;
            h[0] = f2bf(v[0]); h[1] = f2bf(v[1]); h[2] = f2bf(v[2]); h[3] = f2bf(v[3]);
            *(us4*)(xs + ((base + (unsigned)j * 128) ^ swz)) = h;
        }
    }
    __syncthreads();

    f32x4 acc[2][4];

    // =================== layer 0: h0 = sine(x@W0m + b0) ===================
#pragma unroll
    for (int r = 0; r < 2; ++r)
#pragma unroll
        for (int c = 0; c < 4; ++c) acc[r][c] = (f32x4){0.f, 0.f, 0.f, 0.f};

    mm_acc<8, 512>(acc, xs, wb + W0OFF + nb0e, lane);

#pragma unroll
    for (int r = 0; r < 2; ++r) {
#pragma unroll
        for (int j = 0; j < 4; ++j) {
            int row = r * 16 + lhi * 4 + j;
            float* orow = out + (rb + row) * OUTC;
            unsigned hswz = (unsigned)((row & 7) << 4);
#pragma unroll
            for (int c = 0; c < 4; ++c) {
                int col = cb + c * 16 + lcol;
                float z = acc[r][c][j] + b0[col];
                float h = a0v * __sinf(f0v * z) * __expf(-d0v * fabsf(z));
                orow[col] = h;
                *(unsigned short*)(hs + (((unsigned)(row * 1024 + col * 2)) ^ hswz)) = f2bf(h);
            }
        }
    }
    __syncthreads();

    // =================== layer 1: h1 = sine(h0@W1m + b1) + x@S1m ===================
#pragma unroll
    for (int r = 0; r < 2; ++r)
#pragma unroll
        for (int c = 0; c < 4; ++c) acc[r][c] = (f32x4){0.f, 0.f, 0.f, 0.f};

    mm_acc<16, 1024>(acc, hs, wb + W1OFF + nb0e, lane);

#pragma unroll
    for (int c = 0; c < 4; ++c) {
        int col = cb + c * 16 + lcol;
        float bias = b1[col];
#pragma unroll
        for (int r = 0; r < 2; ++r) {
#pragma unroll
            for (int j = 0; j < 4; ++j) {
                float z = acc[r][c][j] + bias;
                acc[r][c][j] = a1v * __sinf(f1v * z) * __expf(-d1v * fabsf(z));
            }
        }
    }
    mm_acc<8, 512>(acc, xs, wb + S1OFF + nb0e, lane);   // accumulate skip on top
    __syncthreads();   // all waves done reading h0 before overwriting hs

#pragma unroll
    for (int r = 0; r < 2; ++r) {
#pragma unroll
        for (int j = 0; j < 4; ++j) {
            int row = r * 16 + lhi * 4 + j;
            float* orow = out + (rb + row) * OUTC + UNITS;
            unsigned hswz = (unsigned)((row & 7) << 4);
#pragma unroll
            for (int c = 0; c < 4; ++c) {
                int col = cb + c * 16 + lcol;
                float h = acc[r][c][j];
                orow[col] = h;
                *(unsigned short*)(hs + (((unsigned)(row * 1024 + col * 2)) ^ hswz)) = f2bf(h);
            }
        }
    }
    __syncthreads();

    // =================== layer 2: h2 = sine(h1@W2m + b2) + x@S2m ===================
#pragma unroll
    for (int r = 0; r < 2; ++r)
#pragma unroll
        for (int c = 0; c < 4; ++c) acc[r][c] = (f32x4){0.f, 0.f, 0.f, 0.f};

    mm_acc<16, 1024>(acc, hs, wb + W2OFF + nb0e, lane);

#pragma unroll
    for (int c = 0; c < 4; ++c) {
        int col = cb + c * 16 + lcol;
        float bias = b2[col];
#pragma unroll
        for (int r = 0; r < 2; ++r) {
#pragma unroll
            for (int j = 0; j < 4; ++j) {
                float z = acc[r][c][j] + bias;
                acc[r][c][j] = a2v * __sinf(f2v * z) * __expf(-d2v * fabsf(z));
            }
        }
    }
    mm_acc<8, 512>(acc, xs, wb + S2OFF + nb0e, lane);

#pragma unroll
    for (int r = 0; r < 2; ++r) {
#pragma unroll
        for (int j = 0; j < 4; ++j) {
            int row = r * 16 + lhi * 4 + j;
            float* orow = out + (rb + row) * OUTC + 2 * UNITS;
#pragma unroll
            for (int c = 0; c < 4; ++c) {
                int col = cb + c * 16 + lcol;
                orow[col] = acc[r][c][j];
            }
        }
    }
}

extern "C" void kernel_launch(void* const* d_in, const int* in_sizes, int n_in,
                              void* d_out, int out_size, void* d_ws, size_t ws_size,
                              hipStream_t stream)
{
    (void)in_sizes; (void)n_in; (void)out_size; (void)ws_size;
    const float* x   = (const float*)d_in[0];
    const float* W0  = (const float*)d_in[1];
    const float* b0  = (const float*)d_in[2];
    const float* M0  = (const float*)d_in[3];
    const float* f0  = (const float*)d_in[4];
    const float* a0  = (const float*)d_in[5];
    const float* d0  = (const float*)d_in[6];
    const float* W1  = (const float*)d_in[7];
    const float* b1  = (const float*)d_in[8];
    const float* M1  = (const float*)d_in[9];
    const float* f1  = (const float*)d_in[10];
    const float* a1  = (const float*)d_in[11];
    const float* d1  = (const float*)d_in[12];
    const float* S1  = (const float*)d_in[13];
    const float* SM1 = (const float*)d_in[14];
    const float* W2  = (const float*)d_in[15];
    const float* b2  = (const float*)d_in[16];
    const float* M2  = (const float*)d_in[17];
    const float* f2  = (const float*)d_in[18];
    const float* a2  = (const float*)d_in[19];
    const float* d2  = (const float*)d_in[20];
    const float* S2  = (const float*)d_in[21];
    const float* SM2 = (const float*)d_in[22];

    unsigned short* wb = (unsigned short*)d_ws;
    float* out = (float*)d_out;

    prep_weights<<<448, 256, 0, stream>>>(W0, M0, W1, M1, W2, M2, S1, SM1, S2, SM2, wb);
    reservoir_main<<<65536 / 32, 512, 0, stream>>>(x, wb, b0, b1, b2,
                                                   f0, a0, d0, f1, a1, d1, f2, a2, d2, out);
}

// Round 5
// 768.970 us; speedup vs baseline: 1.0794x; 1.0767x over previous
//
#include <hip/hip_runtime.h>

// DeepReservoir: out = concat(h0, h1, h2), B=65536, IN=256, U=512
// h0 = sine(x@(W0*M0)+b0); h1 = sine(h0@(W1*M1)+b1) + x@(S1*SM1); h2 likewise.
// prep kernel packs masked bf16 weights in MFMA B-fragment layout into ws;
// main kernel fuses all 3 layers per 32-row tile using 16x16x32 bf16 MFMA.
// R1: 32-row blocks (48KB LDS) -> 2 blocks/CU (occupancy 23->45%), dur flat => not occupancy-bound.
// R4: (a) full-line vectorized writeout via LDS bf16 round-trip (kills 2x write amplification
//     from scalar 4B stores); (b) explicit next-kf A/B register prefetch (hides B-load L2 latency).
// R5: resubmit unchanged (R4 bench lost to GPUAcquisitionTimeout).

#define IN_DIM 256
#define UNITS  512
#define OUTC   1536

typedef __bf16 bf16x8 __attribute__((ext_vector_type(8)));
typedef unsigned short us8 __attribute__((ext_vector_type(8)));
typedef unsigned short us4 __attribute__((ext_vector_type(4)));
typedef float f32x4 __attribute__((ext_vector_type(4)));

// element offsets (bf16) of each packed matrix inside ws
#define W0OFF 0
#define W1OFF 131072
#define W2OFF 393216
#define S1OFF 655360
#define S2OFF 786432

__device__ __forceinline__ unsigned short f2bf(float f) {
    unsigned u = __float_as_uint(f);
    u += 0x7FFFu + ((u >> 16) & 1u);   // round-to-nearest-even
    return (unsigned short)(u >> 16);
}

// ---------------- prep: masked weights -> bf16, packed B-fragment layout ----------------
// Fragment (kf, nb): k in [kf*32, kf*32+32), n in [nb*16, nb*16+16).
// Lane l holds B[k = kf*32 + (l>>4)*8 + i][n = nb*16 + (l&15)], i=0..7 -> 16B per lane.
__global__ __launch_bounds__(256) void prep_weights(
    const float* __restrict__ W0, const float* __restrict__ M0,
    const float* __restrict__ W1, const float* __restrict__ M1,
    const float* __restrict__ W2, const float* __restrict__ M2,
    const float* __restrict__ S1, const float* __restrict__ SM1,
    const float* __restrict__ S2, const float* __restrict__ SM2,
    unsigned short* __restrict__ ws)
{
    int g = blockIdx.x * 256 + threadIdx.x;  // fragment-lane id, 0..114687
    const float* W; const float* M; int obase; int q;
    if (g < 16384)      { W = W0; M = M0;  obase = W0OFF; q = g; }
    else if (g < 49152) { W = W1; M = M1;  obase = W1OFF; q = g - 16384; }
    else if (g < 81920) { W = W2; M = M2;  obase = W2OFF; q = g - 49152; }
    else if (g < 98304) { W = S1; M = SM1; obase = S1OFF; q = g - 81920; }
    else                { W = S2; M = SM2; obase = S2OFF; q = g - 98304; }
    int frag = q >> 6, lane = q & 63;
    int kf = frag >> 5, nb = frag & 31;
    int k0 = kf * 32 + (lane >> 4) * 8;
    int n  = nb * 16 + (lane & 15);
    us8 o;
#pragma unroll
    for (int i = 0; i < 8; ++i) {
        size_t idx = (size_t)(k0 + i) * UNITS + n;
        o[i] = f2bf(W[idx] * M[idx]);
    }
    *(us8*)(ws + obase + (size_t)q * 8) = o;
}

// ---------------- main fused kernel ----------------
// 512 threads = 8 waves; block handles 32 batch rows; wave w -> cols [w*64, w*64+64).
// LDS: xs = 32 x 256 bf16 (pitch 512B, XOR-swizzled), hs = 32 x 512 bf16 (pitch 1024B).
template<int KF, int PITCH>
__device__ __forceinline__ void mm_acc(f32x4 (&acc)[2][4],
    const unsigned char* __restrict__ lsrc,
    const unsigned short* __restrict__ wfrag,   // matrix base + wave's col-frag offset
    int lane)
{
    const int lcol = lane & 15, lhi = lane >> 4;

    us8 bcur[4]; bf16x8 acur[2];
#pragma unroll
    for (int c = 0; c < 4; ++c)
        bcur[c] = *(const us8*)(wfrag + (size_t)((0 * 32 + c) * 64 + lane) * 8);
#pragma unroll
    for (int r = 0; r < 2; ++r) {
        int row = r * 16 + lcol;
        unsigned off = ((unsigned)(row * PITCH + (0 + lhi * 8) * 2)) ^ ((unsigned)((row & 7) << 4));
        acur[r] = __builtin_bit_cast(bf16x8, *(const us8*)(lsrc + off));
    }

#pragma unroll
    for (int kf = 0; kf < KF; ++kf) {
        us8 bnxt[4]; bf16x8 anxt[2];
        if (kf + 1 < KF) {
#pragma unroll
            for (int c = 0; c < 4; ++c)
                bnxt[c] = *(const us8*)(wfrag + (size_t)(((kf + 1) * 32 + c) * 64 + lane) * 8);
#pragma unroll
            for (int r = 0; r < 2; ++r) {
                int row = r * 16 + lcol;
                unsigned off = ((unsigned)(row * PITCH + ((kf + 1) * 32 + lhi * 8) * 2))
                             ^ ((unsigned)((row & 7) << 4));
                anxt[r] = __builtin_bit_cast(bf16x8, *(const us8*)(lsrc + off));
            }
        }
#pragma unroll
        for (int c = 0; c < 4; ++c) {
            bf16x8 b = __builtin_bit_cast(bf16x8, bcur[c]);
#pragma unroll
            for (int r = 0; r < 2; ++r)
                acc[r][c] = __builtin_amdgcn_mfma_f32_16x16x32_bf16(acur[r], b, acc[r][c], 0, 0, 0);
        }
        if (kf + 1 < KF) {
#pragma unroll
            for (int c = 0; c < 4; ++c) bcur[c] = bnxt[c];
#pragma unroll
            for (int r = 0; r < 2; ++r) acur[r] = anxt[r];
        }
    }
}

// vectorized full-line writeout: hs (bf16, swizzled) -> out f32 segment
__device__ __forceinline__ void writeout(const unsigned char* __restrict__ hs,
                                         float* __restrict__ dst, long rb, int t)
{
    int row = t >> 4, c0 = (t & 15) * 32;
    float* o = dst + (rb + row) * OUTC + c0;
    unsigned base = (unsigned)(row * 1024 + c0 * 2);
    unsigned swz  = (unsigned)((row & 7) << 4);
#pragma unroll
    for (int i = 0; i < 4; ++i) {
        us8 v = *(const us8*)(hs + ((base + (unsigned)i * 16) ^ swz));
        f32x4 lo, hi;
#pragma unroll
        for (int j = 0; j < 4; ++j) {
            lo[j] = __uint_as_float((unsigned)v[j] << 16);
            hi[j] = __uint_as_float((unsigned)v[j + 4] << 16);
        }
        *(f32x4*)(o + i * 8)     = lo;
        *(f32x4*)(o + i * 8 + 4) = hi;
    }
}

__global__ __launch_bounds__(512, 4) void reservoir_main(
    const float* __restrict__ x,
    const unsigned short* __restrict__ wb,
    const float* __restrict__ b0, const float* __restrict__ b1, const float* __restrict__ b2,
    const float* __restrict__ pf0, const float* __restrict__ pa0, const float* __restrict__ pd0,
    const float* __restrict__ pf1, const float* __restrict__ pa1, const float* __restrict__ pd1,
    const float* __restrict__ pf2, const float* __restrict__ pa2, const float* __restrict__ pd2,
    float* __restrict__ out)
{
    __shared__ __align__(16) unsigned char lds[49152];
    unsigned char* xs = lds;            // 16 KB
    unsigned char* hs = lds + 16384;    // 32 KB

    const int t = threadIdx.x;
    const int wave = t >> 6, lane = t & 63;
    const int lcol = lane & 15, lhi = lane >> 4;
    const long rb = (long)blockIdx.x * 32;
    const int cb = wave * 64;
    const unsigned nb0e = (unsigned)(wave * 4) * 512;  // element offset of wave's first fragment column

    const float f0v = pf0[0], a0v = pa0[0], d0v = pd0[0];
    const float f1v = pf1[0], a1v = pa1[0], d1v = pd1[0];
    const float f2v = pf2[0], a2v = pa2[0], d2v = pd2[0];

    // ---- stage x tile -> bf16 LDS (swizzled); lane-contiguous 256B per load instr ----
    {
        int r  = t >> 4;            // 0..31
        int cq = (t & 15) * 4;      // float col within 64-float group
        const float* xp = x + (rb + r) * IN_DIM + cq;
        unsigned base = (unsigned)(r * 512 + cq * 2);
        unsigned swz  = (unsigned)((r & 7) << 4);
#pragma unroll
        for (int j = 0; j < 4; ++j) {
            f32x4 v = *(const f32x4*)(xp + j * 64);
            us4 h;
            h[0] = f2bf(v[0]); h[1] = f2bf(v[1]); h[2] = f2bf(v[2]); h[3] = f2bf(v[3]);
            *(us4*)(xs + ((base + (unsigned)j * 128) ^ swz)) = h;
        }
    }
    __syncthreads();   // B1

    f32x4 acc[2][4];

    // =================== layer 0: h0 = sine(x@W0m + b0) -> hs ===================
#pragma unroll
    for (int r = 0; r < 2; ++r)
#pragma unroll
        for (int c = 0; c < 4; ++c) acc[r][c] = (f32x4){0.f, 0.f, 0.f, 0.f};

    mm_acc<8, 512>(acc, xs, wb + W0OFF + nb0e, lane);

    {
        float bias[4];
#pragma unroll
        for (int c = 0; c < 4; ++c) bias[c] = b0[cb + c * 16 + lcol];
#pragma unroll
        for (int r = 0; r < 2; ++r) {
#pragma unroll
            for (int j = 0; j < 4; ++j) {
                int row = r * 16 + lhi * 4 + j;
                unsigned hswz = (unsigned)((row & 7) << 4);
#pragma unroll
                for (int c = 0; c < 4; ++c) {
                    int col = cb + c * 16 + lcol;
                    float z = acc[r][c][j] + bias[c];
                    float h = a0v * __sinf(f0v * z) * __expf(-d0v * fabsf(z));
                    *(unsigned short*)(hs + (((unsigned)(row * 1024 + col * 2)) ^ hswz)) = f2bf(h);
                }
            }
        }
    }
    __syncthreads();   // B2: hs = h0 complete

    // writeout h0 (stores are fire-and-forget; overlap with L1 compute below)
    writeout(hs, out, rb, t);

    // =================== layer 1: h1 = sine(h0@W1m + b1) + x@S1m ===================
#pragma unroll
    for (int r = 0; r < 2; ++r)
#pragma unroll
        for (int c = 0; c < 4; ++c) acc[r][c] = (f32x4){0.f, 0.f, 0.f, 0.f};

    mm_acc<16, 1024>(acc, hs, wb + W1OFF + nb0e, lane);

    {
        float bias[4];
#pragma unroll
        for (int c = 0; c < 4; ++c) bias[c] = b1[cb + c * 16 + lcol];
#pragma unroll
        for (int c = 0; c < 4; ++c) {
#pragma unroll
            for (int r = 0; r < 2; ++r) {
#pragma unroll
                for (int j = 0; j < 4; ++j) {
                    float z = acc[r][c][j] + bias[c];
                    acc[r][c][j] = a1v * __sinf(f1v * z) * __expf(-d1v * fabsf(z));
                }
            }
        }
    }
    mm_acc<8, 512>(acc, xs, wb + S1OFF + nb0e, lane);   // accumulate skip on top
    __syncthreads();   // B3: all reads of h0 (mm + writeout) done

#pragma unroll
    for (int r = 0; r < 2; ++r) {
#pragma unroll
        for (int j = 0; j < 4; ++j) {
            int row = r * 16 + lhi * 4 + j;
            unsigned hswz = (unsigned)((row & 7) << 4);
#pragma unroll
            for (int c = 0; c < 4; ++c) {
                int col = cb + c * 16 + lcol;
                *(unsigned short*)(hs + (((unsigned)(row * 1024 + col * 2)) ^ hswz)) = f2bf(acc[r][c][j]);
            }
        }
    }
    __syncthreads();   // B4: hs = h1 complete

    writeout(hs, out + UNITS, rb, t);

    // =================== layer 2: h2 = sine(h1@W2m + b2) + x@S2m ===================
#pragma unroll
    for (int r = 0; r < 2; ++r)
#pragma unroll
        for (int c = 0; c < 4; ++c) acc[r][c] = (f32x4){0.f, 0.f, 0.f, 0.f};

    mm_acc<16, 1024>(acc, hs, wb + W2OFF + nb0e, lane);

    {
        float bias[4];
#pragma unroll
        for (int c = 0; c < 4; ++c) bias[c] = b2[cb + c * 16 + lcol];
#pragma unroll
        for (int c = 0; c < 4; ++c) {
#pragma unroll
            for (int r = 0; r < 2; ++r) {
#pragma unroll
                for (int j = 0; j < 4; ++j) {
                    float z = acc[r][c][j] + bias[c];
                    acc[r][c][j] = a2v * __sinf(f2v * z) * __expf(-d2v * fabsf(z));
                }
            }
        }
    }
    mm_acc<8, 512>(acc, xs, wb + S2OFF + nb0e, lane);
    __syncthreads();   // B5: all reads of h1 (mm + writeout) done

#pragma unroll
    for (int r = 0; r < 2; ++r) {
#pragma unroll
        for (int j = 0; j < 4; ++j) {
            int row = r * 16 + lhi * 4 + j;
            unsigned hswz = (unsigned)((row & 7) << 4);
#pragma unroll
            for (int c = 0; c < 4; ++c) {
                int col = cb + c * 16 + lcol;
                *(unsigned short*)(hs + (((unsigned)(row * 1024 + col * 2)) ^ hswz)) = f2bf(acc[r][c][j]);
            }
        }
    }
    __syncthreads();   // B6: hs = h2 complete

    writeout(hs, out + 2 * UNITS, rb, t);
}

extern "C" void kernel_launch(void* const* d_in, const int* in_sizes, int n_in,
                              void* d_out, int out_size, void* d_ws, size_t ws_size,
                              hipStream_t stream)
{
    (void)in_sizes; (void)n_in; (void)out_size; (void)ws_size;
    const float* x   = (const float*)d_in[0];
    const float* W0  = (const float*)d_in[1];
    const float* b0  = (const float*)d_in[2];
    const float* M0  = (const float*)d_in[3];
    const float* f0  = (const float*)d_in[4];
    const float* a0  = (const float*)d_in[5];
    const float* d0  = (const float*)d_in[6];
    const float* W1  = (const float*)d_in[7];
    const float* b1  = (const float*)d_in[8];
    const float* M1  = (const float*)d_in[9];
    const float* f1  = (const float*)d_in[10];
    const float* a1  = (const float*)d_in[11];
    const float* d1  = (const float*)d_in[12];
    const float* S1  = (const float*)d_in[13];
    const float* SM1 = (const float*)d_in[14];
    const float* W2  = (const float*)d_in[15];
    const float* b2  = (const float*)d_in[16];
    const float* M2  = (const float*)d_in[17];
    const float* f2  = (const float*)d_in[18];
    const float* a2  = (const float*)d_in[19];
    const float* d2  = (const float*)d_in[20];
    const float* S2  = (const float*)d_in[21];
    const float* SM2 = (const float*)d_in[22];

    unsigned short* wb = (unsigned short*)d_ws;
    float* out = (float*)d_out;

    prep_weights<<<448, 256, 0, stream>>>(W0, M0, W1, M1, W2, M2, S1, SM1, S2, SM2, wb);
    reservoir_main<<<65536 / 32, 512, 0, stream>>>(x, wb, b0, b1, b2,
                                                   f0, a0, d0, f1, a1, d1, f2, a2, d2, out);
}